// Round 3
// baseline (390.331 us; speedup 1.0000x reference)
//
#include <hip/hip_runtime.h>
#include <math.h>

// Problem constants (fixed by the reference)
#define BB 256
#define TT 512
#define DD 128
#define HH 128
#define GG 512   // 4*H
#define OO 64

#define LOG2E    1.44269504088896340736f
#define TWOLOG2E 2.88539008177792681472f

typedef _Float16 half8 __attribute__((ext_vector_type(8)));
typedef float    f32x4 __attribute__((ext_vector_type(4)));

// lane ^ 16 value exchange within a wave (BitMode swizzle: xor=16, and=0x1F)
__device__ __forceinline__ float swz16(float v) {
    int i = __builtin_bit_cast(int, v);
    i = __builtin_amdgcn_ds_swizzle(i, 0x401F);
    return __builtin_bit_cast(float, i);
}

// ---------------------------------------------------------------------------
// Kernel 1 (fused): blocks [0,TT): xg; blocks [TT,TT+16): weight packing.
//
// PRESCALE: W_hh rows and xg are multiplied by log2e (gates i,f,o) or
// 2*log2e (gate g) at pack time, so every activation in the scan is a bare
// v_exp_f32 (=2^x) with sign/abs folded into input modifiers. c is kept in
// 2*log2e-scaled units (scale-invariant recurrence, see scan kernel).
//
// xg[t][j][gate]: input-gate contribution, PACKED per-hidden-index so a scan
// lane reads i,f,g,o as one 16-B vector. Only batch 255 matters:
// y.reshape(T,B,O)[-1] -> flat rows (b=255, t>=256); b=255's scan needs all t.
//
// wpack (4-wave layout, r3/r8-verified fragment math):
//   wave w(0..3), n-tile nt(0..7), k-tile kt(0..3), lane l:
//   row = (nt>>1)*128 + (nt&1)*16 + w*32 + (l&15); off = kt*32 + (l>>4)*8
//   dst = Wp[((w*32 + nt*4 + kt)*64 + l)*8 .. +8]
// ---------------------------------------------------------------------------
__global__ __launch_bounds__(512) void xgpack_kernel(
    const float* __restrict__ x,
    const float* __restrict__ W_ih,
    const float* __restrict__ b_ih,
    const float* __restrict__ b_hh,
    const float* __restrict__ W_hh,
    float* __restrict__ xg,
    _Float16* __restrict__ Wp)
{
    if (blockIdx.x >= TT) {   // ---- weight-packing blocks ----
        const int g = (blockIdx.x - TT) * 512 + threadIdx.x;  // 0..8191
        const int fid = g >> 6, l = g & 63;
        const int w = fid >> 5, rem = fid & 31, nt = rem >> 2, kt = rem & 3;
        const int quad = l >> 4, col = l & 15;
        const int row = (nt >> 1) * 128 + (nt & 1) * 16 + w * 32 + col;
        const int off = kt * 32 + quad * 8;
        const float ws = ((row >> 7) == 2) ? TWOLOG2E : LOG2E;  // g-gate rows 2x
        const float* s = W_hh + row * HH + off;
        _Float16* d = Wp + (size_t)g * 8;
#pragma unroll
        for (int i = 0; i < 8; i++) d[i] = (_Float16)(s[i] * ws);
        return;
    }

    const int t = blockIdx.x;
    const int g = threadIdx.x;

    __shared__ __align__(16) float xs[DD];
    if (g < DD) xs[g] = x[(255 * TT + t) * DD + g];
    __syncthreads();

    const float4* __restrict__ wrow = (const float4*)(W_ih + g * DD);
    const float4* __restrict__ xv   = (const float4*)xs;

    float a0 = 0.f, a1 = 0.f, a2 = 0.f, a3 = 0.f;
#pragma unroll
    for (int i = 0; i < DD / 4; i += 4) {
        float4 w0 = wrow[i + 0], w1 = wrow[i + 1], w2 = wrow[i + 2], w3 = wrow[i + 3];
        float4 h0 = xv[i + 0],  h1 = xv[i + 1],  h2 = xv[i + 2],  h3 = xv[i + 3];
        a0 += w0.x * h0.x + w0.y * h0.y + w0.z * h0.z + w0.w * h0.w;
        a1 += w1.x * h1.x + w1.y * h1.y + w1.z * h1.z + w1.w * h1.w;
        a2 += w2.x * h2.x + w2.y * h2.y + w2.z * h2.z + w2.w * h2.w;
        a3 += w3.x * h3.x + w3.y * h3.y + w3.z * h3.z + w3.w * h3.w;
    }
    const float scale = ((g >> 7) == 2) ? TWOLOG2E : LOG2E;
    const float val = ((a0 + a1) + (a2 + a3) + b_ih[g] + b_hh[g]) * scale;
    xg[t * GG + (g & 127) * 4 + (g >> 7)] = val;   // packed [t][j][gate]
}

// ---------------------------------------------------------------------------
// Kernel 2: MFMA LSTM scan (batch 255). 1 block, 256 threads = 4 waves.
// r3-verified tile map: wave w owns 8 n-tiles (4 gates x 2 halves) of hidden
// slice [32w,32w+32); lane updates jsel = wbase + 16*sel + col.
//
// R3 (this revision): revert R2's regressions, keep its wins, and split the
// transcendental work across the duplicated lane pair.
//  * REVERTED to laundered-Z accumulator seeds + post-MFMA xg adds (R2's
//    XCUR-seeded accumulators forced per-step v_mov quad materialization on
//    the MFMA issue path) and to the R1 prefetch (temp xpf at step start,
//    register copy at end -- the in-place reload's use-wait crossed the
//    divergent store, defeating static vmcnt counting).
//  * KEPT exp2-prescaled weights/biases (no muls on the activation chain)
//    and sign-folded fma tails.
//  * NEW pair-split transcendentals: each jsel is owned by 2 lanes (quad
//    pairs 0<->1, 2<->3 -- MFMA rows replicated, so C[0] is identical).
//    Even quads compute sigmoid(i),sigmoid(f); odd quads tanh(g),sigmoid(o)
//    (branchless cndmask with abs/neg modifiers); exchange via
//    ds_swizzle(lane^16). Wave TRANS ops drop 10 -> 6 (v_exp/v_rcp are
//    quarter-rate: ~16 cyc issue each, so this cuts ~64 cyc/step of
//    TRANS-pipe serialization at the cost of 2 ds_swizzle + ~6 cndmask).
// Kept from R1: RAW lgkmcnt(0)+s_barrier asm (global loads/stores stay in
// flight across barriers), one-time B-fragment launder, per-step global hs
// ring store, waves_per_eu(1,1).
// ---------------------------------------------------------------------------
__global__
__attribute__((amdgpu_flat_work_group_size(256, 256), amdgpu_waves_per_eu(1, 1)))
void scan_kernel(
    const _Float16* __restrict__ Wp,
    const float* __restrict__ xgp,
    float* __restrict__ hs)
{
    const int tid  = threadIdx.x;
    const int lane = tid & 63;
    const int w    = tid >> 6;        // wave id 0..3
    const int col  = lane & 15;
    const int quad = lane >> 4;
    const int wbase = w * 32;
    const bool sel  = (lane >= 32);
    const bool odd  = (quad & 1);     // pair-split role: odd owns {g,o}
    const int jsel  = wbase + (sel ? 16 : 0) + col; // hidden index this lane updates
    const int aoff  = quad * 8;
    const bool wr   = (quad == 0) || (quad == 3);   // one writer per hidden index

    __shared__ __align__(16) _Float16 h_lds[2][HH];          // 512 B total

    // ---- B-fragments: contiguous 16-B loads from the packed buffer ----
#define BLOADP(nt, kt) \
    half8 B##nt##_##kt = *(const half8*)(Wp + (((w * 32 + (nt) * 4 + (kt)) * 64 + lane) * 8));
#define FOR_KT(X, nt) X(nt, 0) X(nt, 1) X(nt, 2) X(nt, 3)
#define FOR_NT(X) FOR_KT(X, 0) FOR_KT(X, 1) FOR_KT(X, 2) FOR_KT(X, 3) \
                  FOR_KT(X, 4) FOR_KT(X, 5) FOR_KT(X, 6) FOR_KT(X, 7)
    FOR_NT(BLOADP)

    // ---- ONE-TIME launder: opaque-define the fragments (cannot be sunk) ----
    asm volatile("" : "+v"(B0_0), "+v"(B0_1), "+v"(B0_2), "+v"(B0_3),
                      "+v"(B1_0), "+v"(B1_1), "+v"(B1_2), "+v"(B1_3),
                      "+v"(B2_0), "+v"(B2_1), "+v"(B2_2), "+v"(B2_3),
                      "+v"(B3_0), "+v"(B3_1), "+v"(B3_2), "+v"(B3_3));
    asm volatile("" : "+v"(B4_0), "+v"(B4_1), "+v"(B4_2), "+v"(B4_3),
                      "+v"(B5_0), "+v"(B5_1), "+v"(B5_2), "+v"(B5_3),
                      "+v"(B6_0), "+v"(B6_1), "+v"(B6_2), "+v"(B6_3),
                      "+v"(B7_0), "+v"(B7_1), "+v"(B7_2), "+v"(B7_3));

    if (tid < HH) h_lds[0][tid] = (_Float16)0.f;

    // persistent zero accumulator seed (4 VGPRs, laundered so it is never
    // rematerialized as per-step v_movs)
    f32x4 Z = {0.f, 0.f, 0.f, 0.f};
    asm volatile("" : "+v"(Z));

    // 2-deep register prefetch of the packed gate biases (16 B/lane)
    const float* __restrict__ xgl = xgp + jsel * 4;
    f32x4 xg0 = *(const f32x4*)(xgl + 0 * GG);
    f32x4 xg1 = *(const f32x4*)(xgl + 1 * GG);

    float c = 0.f;   // in 2*log2e-scaled units
    __syncthreads();   // one-time full barrier (drains prologue loads too)

#define MM(a, b, cc) __builtin_amdgcn_mfma_f32_16x16x32_f16((a), (b), (cc), 0, 0, 0)
#define STEP(par, XCUR) do {                                                            \
    const int t = t2 + (par);                                                           \
    f32x4 xpf = *(const f32x4*)(xgl + ((t + 2) & (TT - 1)) * GG);                       \
    const _Float16* hl = h_lds[(par)];                                                  \
    half8 A0 = *(const half8*)(hl +  0 + aoff);                                         \
    half8 A1 = *(const half8*)(hl + 32 + aoff);                                         \
    half8 A2 = *(const half8*)(hl + 64 + aoff);                                         \
    half8 A3 = *(const half8*)(hl + 96 + aoff);                                         \
    f32x4 C0, C1, C2, C3, C4, C5, C6, C7;                                               \
    C4 = MM(A0, B4_0, Z);  C5 = MM(A0, B5_0, Z);  C0 = MM(A0, B0_0, Z);                 \
    C1 = MM(A0, B1_0, Z);  C2 = MM(A0, B2_0, Z);  C3 = MM(A0, B3_0, Z);                 \
    C6 = MM(A0, B6_0, Z);  C7 = MM(A0, B7_0, Z);                                        \
    C4 = MM(A1, B4_1, C4); C5 = MM(A1, B5_1, C5); C0 = MM(A1, B0_1, C0);                \
    C1 = MM(A1, B1_1, C1); C2 = MM(A1, B2_1, C2); C3 = MM(A1, B3_1, C3);                \
    C6 = MM(A1, B6_1, C6); C7 = MM(A1, B7_1, C7);                                       \
    C4 = MM(A2, B4_2, C4); C5 = MM(A2, B5_2, C5); C0 = MM(A2, B0_2, C0);                \
    C1 = MM(A2, B1_2, C1); C2 = MM(A2, B2_2, C2); C3 = MM(A2, B3_2, C3);                \
    C6 = MM(A2, B6_2, C6); C7 = MM(A2, B7_2, C7);                                       \
    C4 = MM(A3, B4_3, C4); C5 = MM(A3, B5_3, C5); C0 = MM(A3, B0_3, C0);                \
    C1 = MM(A3, B1_3, C1); C2 = MM(A3, B2_3, C2); C3 = MM(A3, B3_3, C3);                \
    C6 = MM(A3, B6_3, C6); C7 = MM(A3, B7_3, C7);                                       \
    /* pre-activations (exp2-prescaled): pg by 2log2e, others by log2e */               \
    float pi = (sel ? C1[0] : C0[0]) + (XCUR).x;                                        \
    float pf = (sel ? C3[0] : C2[0]) + (XCUR).y;                                        \
    float pg = (sel ? C5[0] : C4[0]) + (XCUR).z;                                        \
    float po = (sel ? C7[0] : C6[0]) + (XCUR).w;                                        \
    /* pair-split: even quads own {i,f}, odd quads own {g,o} */                         \
    float pa = odd ? pg : pi;                                                           \
    float pb = odd ? po : pf;                                                           \
    float ax = odd ? fabsf(pa) : -pa;                                                   \
    float ea = __builtin_amdgcn_exp2f(ax);                                              \
    float ra = __builtin_amdgcn_rcpf(1.0f + ea);                                        \
    float T  = copysignf(TWOLOG2E, pa);                                                 \
    float va = odd ? fmaf(-2.0f * T, ra, T) : ra;   /* odd: gvs(scaled), even: iv */    \
    float eb = __builtin_amdgcn_exp2f(-pb);                                             \
    float vb = __builtin_amdgcn_rcpf(1.0f + eb);    /* odd: ov, even: fv */             \
    float sa = swz16(va);                                                               \
    float sb = swz16(vb);                                                               \
    float iv  = odd ? sa : va;                                                          \
    float gvs = odd ? va : sa;                                                          \
    float fv  = odd ? sb : vb;                                                          \
    float ov  = odd ? vb : sb;                                                          \
    c = fmaf(fv, c, iv * gvs);          /* c stays in 2log2e-scaled units */            \
    float Ec = __builtin_amdgcn_exp2f(fabsf(c));                                        \
    float rc = __builtin_amdgcn_rcpf(Ec + 1.0f);                                        \
    float Ao = copysignf(ov, c);                                                        \
    float hval = fmaf(-2.0f * Ao, rc, Ao);                                              \
    if (wr) {                                                                           \
        h_lds[1 - (par)][jsel] = (_Float16)hval;                                        \
        hs[(t & (BB - 1)) * HH + jsel] = hval; /* ring: t<256 slots overwritten */      \
    }                                                                                   \
    asm volatile("s_waitcnt lgkmcnt(0)\n\ts_barrier" ::: "memory");                     \
    (XCUR) = xpf;                                                                       \
} while (0)

    for (int t2 = 0; t2 < TT; t2 += 2) {
        STEP(0, xg0);   // reads h_lds[0], writes h_lds[1]
        STEP(1, xg1);   // reads h_lds[1], writes h_lds[0]
    }
#undef STEP
#undef MM
}

// ---------------------------------------------------------------------------
// Kernel 3: out[r,:] = W2 @ (W1 @ hs[r] + b1) + b2  (no activation in ref)
// ---------------------------------------------------------------------------
__global__ __launch_bounds__(128) void mlp_kernel(
    const float* __restrict__ hs,
    const float* __restrict__ W1,
    const float* __restrict__ b1,
    const float* __restrict__ W2,
    const float* __restrict__ b2,
    float* __restrict__ out)
{
    const int r = blockIdx.x;
    const int j = threadIdx.x;

    __shared__ __align__(16) float hsh[HH];
    __shared__ __align__(16) float z[HH];

    hsh[j] = hs[r * HH + j];
    __syncthreads();

    {
        const float4* __restrict__ wrow = (const float4*)(W1 + j * HH);
        const float4* __restrict__ hv   = (const float4*)hsh;
        float acc = b1[j];
#pragma unroll
        for (int i = 0; i < 32; i++) {
            float4 ww = wrow[i], h = hv[i];
            acc += ww.x * h.x + ww.y * h.y + ww.z * h.z + ww.w * h.w;
        }
        z[j] = acc;
    }
    __syncthreads();

    if (j < OO) {
        const float4* __restrict__ wrow = (const float4*)(W2 + j * HH);
        const float4* __restrict__ zv   = (const float4*)z;
        float acc = b2[j];
#pragma unroll
        for (int i = 0; i < 32; i++) {
            float4 ww = wrow[i], zz = zv[i];
            acc += ww.x * zz.x + ww.y * zz.y + ww.z * zz.z + ww.w * zz.w;
        }
        out[r * OO + j] = acc;
    }
}

// ---------------------------------------------------------------------------
// Launch. Inputs: 0:x 1:W_ih 2:W_hh 3:b_ih 4:b_hh 5:W1 6:b1 7:W2 8:b2
// ws: xg packed (1 MB) | hs (128 KB) | Wp packed f16 frags (128 KB)
// ---------------------------------------------------------------------------
extern "C" void kernel_launch(void* const* d_in, const int* in_sizes, int n_in,
                              void* d_out, int out_size, void* d_ws, size_t ws_size,
                              hipStream_t stream) {
    const float* x    = (const float*)d_in[0];
    const float* W_ih = (const float*)d_in[1];
    const float* W_hh = (const float*)d_in[2];
    const float* b_ih = (const float*)d_in[3];
    const float* b_hh = (const float*)d_in[4];
    const float* W1   = (const float*)d_in[5];
    const float* b1   = (const float*)d_in[6];
    const float* W2   = (const float*)d_in[7];
    const float* b2   = (const float*)d_in[8];
    float* out = (float*)d_out;

    float*    xg = (float*)d_ws;                 // T*4H   = 262144 f32 (packed)
    float*    hs = xg + TT * GG;                 // 256*H  =  32768 f32
    _Float16* Wp = (_Float16*)(hs + BB * HH);    // 4H*H   =  65536 f16 (packed frags)

    xgpack_kernel<<<TT + 16, 512, 0, stream>>>(x, W_ih, b_ih, b_hh, W_hh, xg, Wp);
    scan_kernel<<<1, 256, 0, stream>>>(Wp, xg, hs);
    mlp_kernel<<<BB, 128, 0, stream>>>(hs, W1, b1, W2, b2, out);
}

// Round 4
// 330.697 us; speedup vs baseline: 1.1803x; 1.1803x over previous
//
#include <hip/hip_runtime.h>
#include <math.h>

// Problem constants (fixed by the reference)
#define BB 256
#define TT 512
#define DD 128
#define HH 128
#define GG 512   // 4*H
#define OO 64

#define LOG2E    1.44269504088896340736f
#define TWOLOG2E 2.88539008177792681472f

typedef _Float16 half8 __attribute__((ext_vector_type(8)));
typedef float    f32x4 __attribute__((ext_vector_type(4)));

// ---------------------------------------------------------------------------
// Kernel 1 (fused): blocks [0,TT): xg; blocks [TT,TT+16): weight packing.
//
// PRESCALE: W_hh rows and xg are multiplied by log2e (gates i,f,o) or
// 2*log2e (gate g) at pack time, so every activation in the scan is a bare
// v_exp_f32 (=2^x) with sign/abs folded into input modifiers. c is kept in
// 2*log2e-scaled units (scale-invariant recurrence, see scan kernel).
//
// xg[t][j][gate]: input-gate contribution, PACKED per-hidden-index so a scan
// lane reads i,f,g,o as one 16-B vector. Only batch 255 matters:
// y.reshape(T,B,O)[-1] -> flat rows (b=255, t>=256); b=255's scan needs all t.
//
// wpack (4-wave layout, r3/r8-verified fragment math):
//   wave w(0..3), n-tile nt(0..7), k-tile kt(0..3), lane l:
//   row = (nt>>1)*128 + (nt&1)*16 + w*32 + (l&15); off = kt*32 + (l>>4)*8
//   dst = Wp[((w*32 + nt*4 + kt)*64 + l)*8 .. +8]
// ---------------------------------------------------------------------------
__global__ __launch_bounds__(512) void xgpack_kernel(
    const float* __restrict__ x,
    const float* __restrict__ W_ih,
    const float* __restrict__ b_ih,
    const float* __restrict__ b_hh,
    const float* __restrict__ W_hh,
    float* __restrict__ xg,
    _Float16* __restrict__ Wp)
{
    if (blockIdx.x >= TT) {   // ---- weight-packing blocks ----
        const int g = (blockIdx.x - TT) * 512 + threadIdx.x;  // 0..8191
        const int fid = g >> 6, l = g & 63;
        const int w = fid >> 5, rem = fid & 31, nt = rem >> 2, kt = rem & 3;
        const int quad = l >> 4, col = l & 15;
        const int row = (nt >> 1) * 128 + (nt & 1) * 16 + w * 32 + col;
        const int off = kt * 32 + quad * 8;
        const float ws = ((row >> 7) == 2) ? TWOLOG2E : LOG2E;  // g-gate rows 2x
        const float* s = W_hh + row * HH + off;
        _Float16* d = Wp + (size_t)g * 8;
#pragma unroll
        for (int i = 0; i < 8; i++) d[i] = (_Float16)(s[i] * ws);
        return;
    }

    const int t = blockIdx.x;
    const int g = threadIdx.x;

    __shared__ __align__(16) float xs[DD];
    if (g < DD) xs[g] = x[(255 * TT + t) * DD + g];
    __syncthreads();

    const float4* __restrict__ wrow = (const float4*)(W_ih + g * DD);
    const float4* __restrict__ xv   = (const float4*)xs;

    float a0 = 0.f, a1 = 0.f, a2 = 0.f, a3 = 0.f;
#pragma unroll
    for (int i = 0; i < DD / 4; i += 4) {
        float4 w0 = wrow[i + 0], w1 = wrow[i + 1], w2 = wrow[i + 2], w3 = wrow[i + 3];
        float4 h0 = xv[i + 0],  h1 = xv[i + 1],  h2 = xv[i + 2],  h3 = xv[i + 3];
        a0 += w0.x * h0.x + w0.y * h0.y + w0.z * h0.z + w0.w * h0.w;
        a1 += w1.x * h1.x + w1.y * h1.y + w1.z * h1.z + w1.w * h1.w;
        a2 += w2.x * h2.x + w2.y * h2.y + w2.z * h2.z + w2.w * h2.w;
        a3 += w3.x * h3.x + w3.y * h3.y + w3.z * h3.z + w3.w * h3.w;
    }
    const float scale = ((g >> 7) == 2) ? TWOLOG2E : LOG2E;
    const float val = ((a0 + a1) + (a2 + a3) + b_ih[g] + b_hh[g]) * scale;
    xg[t * GG + (g & 127) * 4 + (g >> 7)] = val;   // packed [t][j][gate]
}

// ---------------------------------------------------------------------------
// Kernel 2: MFMA LSTM scan (batch 255). 1 block, 256 threads = 4 waves.
// r3-verified tile map: wave w owns 8 n-tiles (4 gates x 2 halves) of hidden
// slice [32w,32w+32); lane updates jsel = wbase + 16*sel + col.
//
// R4 = R1 structure (the 222 us best: Z-seeded accumulators, xpf temp
// prefetch, straight per-lane epilogue, RAW lgkmcnt(0)+s_barrier) plus:
//  * exp2-prescaled weights/biases + sign-folded fma tails (carried through
//    R2/R3 with identical absmax; removes 2 serial v_muls from the chain).
//  * h history kept in a 128 KB LDS ring (hs_l) instead of per-step GLOBAL
//    stores, dumped once at the end. Theory: vmcnt retires IN ORDER, so the
//    per-step (XCUR)=xpf copy's wait for the xpf load transitively waited
//    for the PREVIOUS step's global hs store to retire (~hundreds of cyc of
//    store-ack latency dragged onto the serial chain). With the store gone,
//    the only vmem op per step is the xpf load, issued a full step (~1000
//    cyc) ahead -> its wait is always satisfied. Also removes the store
//    issue + exec-masked branch body from the loop.
// NOT re-tried (measured regressions): accumulator xg-seeding (R2, +25 us:
// per-step v_mov quads on the MFMA issue path), in-place XCUR reload (R2:
// vmcnt wait crossed the divergent store), pair-split transcendentals via
// ds_swizzle (R3, +43 us: swizzle latency lands on the serial chain).
// ---------------------------------------------------------------------------
__global__
__attribute__((amdgpu_flat_work_group_size(256, 256), amdgpu_waves_per_eu(1, 1)))
void scan_kernel(
    const _Float16* __restrict__ Wp,
    const float* __restrict__ xgp,
    float* __restrict__ hs)
{
    const int tid  = threadIdx.x;
    const int lane = tid & 63;
    const int w    = tid >> 6;        // wave id 0..3
    const int col  = lane & 15;
    const int quad = lane >> 4;
    const int wbase = w * 32;
    const bool sel  = (lane >= 32);
    const int jsel  = wbase + (sel ? 16 : 0) + col; // hidden index this lane updates
    const int aoff  = quad * 8;
    const bool wr   = (quad == 0) || (quad == 3);   // one writer per hidden index

    __shared__ __align__(16) _Float16 h_lds[2][HH];          // 512 B
    __shared__ __align__(16) float hs_l[BB * HH];            // 128 KB ring

    // ---- B-fragments: contiguous 16-B loads from the packed buffer ----
#define BLOADP(nt, kt) \
    half8 B##nt##_##kt = *(const half8*)(Wp + (((w * 32 + (nt) * 4 + (kt)) * 64 + lane) * 8));
#define FOR_KT(X, nt) X(nt, 0) X(nt, 1) X(nt, 2) X(nt, 3)
#define FOR_NT(X) FOR_KT(X, 0) FOR_KT(X, 1) FOR_KT(X, 2) FOR_KT(X, 3) \
                  FOR_KT(X, 4) FOR_KT(X, 5) FOR_KT(X, 6) FOR_KT(X, 7)
    FOR_NT(BLOADP)

    // ---- ONE-TIME launder: opaque-define the fragments (cannot be sunk) ----
    asm volatile("" : "+v"(B0_0), "+v"(B0_1), "+v"(B0_2), "+v"(B0_3),
                      "+v"(B1_0), "+v"(B1_1), "+v"(B1_2), "+v"(B1_3),
                      "+v"(B2_0), "+v"(B2_1), "+v"(B2_2), "+v"(B2_3),
                      "+v"(B3_0), "+v"(B3_1), "+v"(B3_2), "+v"(B3_3));
    asm volatile("" : "+v"(B4_0), "+v"(B4_1), "+v"(B4_2), "+v"(B4_3),
                      "+v"(B5_0), "+v"(B5_1), "+v"(B5_2), "+v"(B5_3),
                      "+v"(B6_0), "+v"(B6_1), "+v"(B6_2), "+v"(B6_3),
                      "+v"(B7_0), "+v"(B7_1), "+v"(B7_2), "+v"(B7_3));

    if (tid < HH) h_lds[0][tid] = (_Float16)0.f;

    // persistent zero accumulator seed (4 VGPRs, laundered so it is never
    // rematerialized as per-step v_movs)
    f32x4 Z = {0.f, 0.f, 0.f, 0.f};
    asm volatile("" : "+v"(Z));

    // 2-deep register prefetch of the packed gate biases (16 B/lane)
    const float* __restrict__ xgl = xgp + jsel * 4;
    f32x4 xg0 = *(const f32x4*)(xgl + 0 * GG);
    f32x4 xg1 = *(const f32x4*)(xgl + 1 * GG);

    float c = 0.f;   // in 2*log2e-scaled units
    __syncthreads();   // one-time full barrier (drains prologue loads too)

#define MM(a, b, cc) __builtin_amdgcn_mfma_f32_16x16x32_f16((a), (b), (cc), 0, 0, 0)
#define STEP(par, XCUR) do {                                                            \
    const int t = t2 + (par);                                                           \
    f32x4 xpf = *(const f32x4*)(xgl + ((t + 2) & (TT - 1)) * GG);                       \
    const _Float16* hl = h_lds[(par)];                                                  \
    half8 A0 = *(const half8*)(hl +  0 + aoff);                                         \
    half8 A1 = *(const half8*)(hl + 32 + aoff);                                         \
    half8 A2 = *(const half8*)(hl + 64 + aoff);                                         \
    half8 A3 = *(const half8*)(hl + 96 + aoff);                                         \
    f32x4 C0, C1, C2, C3, C4, C5, C6, C7;                                               \
    C4 = MM(A0, B4_0, Z);  C5 = MM(A0, B5_0, Z);  C0 = MM(A0, B0_0, Z);                 \
    C1 = MM(A0, B1_0, Z);  C2 = MM(A0, B2_0, Z);  C3 = MM(A0, B3_0, Z);                 \
    C6 = MM(A0, B6_0, Z);  C7 = MM(A0, B7_0, Z);                                        \
    C4 = MM(A1, B4_1, C4); C5 = MM(A1, B5_1, C5); C0 = MM(A1, B0_1, C0);                \
    C1 = MM(A1, B1_1, C1); C2 = MM(A1, B2_1, C2); C3 = MM(A1, B3_1, C3);                \
    C6 = MM(A1, B6_1, C6); C7 = MM(A1, B7_1, C7);                                       \
    C4 = MM(A2, B4_2, C4); C5 = MM(A2, B5_2, C5); C0 = MM(A2, B0_2, C0);                \
    C1 = MM(A2, B1_2, C1); C2 = MM(A2, B2_2, C2); C3 = MM(A2, B3_2, C3);                \
    C6 = MM(A2, B6_2, C6); C7 = MM(A2, B7_2, C7);                                       \
    C4 = MM(A3, B4_3, C4); C5 = MM(A3, B5_3, C5); C0 = MM(A3, B0_3, C0);                \
    C1 = MM(A3, B1_3, C1); C2 = MM(A3, B2_3, C2); C3 = MM(A3, B3_3, C3);                \
    C6 = MM(A3, B6_3, C6); C7 = MM(A3, B7_3, C7);                                       \
    /* pre-activations (exp2-prescaled): pg by 2log2e, others by log2e */               \
    float pi = (sel ? C1[0] : C0[0]) + (XCUR).x;                                        \
    float pf = (sel ? C3[0] : C2[0]) + (XCUR).y;                                        \
    float pg = (sel ? C5[0] : C4[0]) + (XCUR).z;                                        \
    float po = (sel ? C7[0] : C6[0]) + (XCUR).w;                                        \
    float iv = __builtin_amdgcn_rcpf(1.0f + __builtin_amdgcn_exp2f(-pi));               \
    float fv = __builtin_amdgcn_rcpf(1.0f + __builtin_amdgcn_exp2f(-pf));               \
    float ov = __builtin_amdgcn_rcpf(1.0f + __builtin_amdgcn_exp2f(-po));               \
    float Eg = __builtin_amdgcn_exp2f(fabsf(pg));                                       \
    float rg = __builtin_amdgcn_rcpf(Eg + 1.0f);                                        \
    float T  = copysignf(TWOLOG2E, pg);                                                 \
    float gvs = fmaf(-2.0f * T, rg, T);  /* = 2log2e * tanh(raw_g) */                   \
    c = fmaf(fv, c, iv * gvs);           /* c stays in 2log2e-scaled units */           \
    float Ec = __builtin_amdgcn_exp2f(fabsf(c));                                        \
    float rc = __builtin_amdgcn_rcpf(Ec + 1.0f);                                        \
    float Ao = copysignf(ov, c);                                                        \
    float hval = fmaf(-2.0f * Ao, rc, Ao);                                              \
    if (wr) {                                                                           \
        h_lds[1 - (par)][jsel] = (_Float16)hval;                                        \
        hs_l[(t & (BB - 1)) * HH + jsel] = hval; /* LDS ring, same lgkm wait */         \
    }                                                                                   \
    asm volatile("s_waitcnt lgkmcnt(0)\n\ts_barrier" ::: "memory");                     \
    (XCUR) = xpf;                                                                       \
} while (0)

    for (int t2 = 0; t2 < TT; t2 += 2) {
        STEP(0, xg0);   // reads h_lds[0], writes h_lds[1]
        STEP(1, xg1);   // reads h_lds[1], writes h_lds[0]
    }
#undef STEP
#undef MM

    // dump hs ring (128 KB LDS -> global, coalesced); last STEP's
    // lgkmcnt(0)+barrier already made all hs_l writes visible
    const f32x4* s = (const f32x4*)hs_l;
    f32x4* d = (f32x4*)hs;
#pragma unroll 4
    for (int i = tid; i < BB * HH / 4; i += 256) d[i] = s[i];
}

// ---------------------------------------------------------------------------
// Kernel 3: out[r,:] = W2 @ (W1 @ hs[r] + b1) + b2  (no activation in ref)
// ---------------------------------------------------------------------------
__global__ __launch_bounds__(128) void mlp_kernel(
    const float* __restrict__ hs,
    const float* __restrict__ W1,
    const float* __restrict__ b1,
    const float* __restrict__ W2,
    const float* __restrict__ b2,
    float* __restrict__ out)
{
    const int r = blockIdx.x;
    const int j = threadIdx.x;

    __shared__ __align__(16) float hsh[HH];
    __shared__ __align__(16) float z[HH];

    hsh[j] = hs[r * HH + j];
    __syncthreads();

    {
        const float4* __restrict__ wrow = (const float4*)(W1 + j * HH);
        const float4* __restrict__ hv   = (const float4*)hsh;
        float acc = b1[j];
#pragma unroll
        for (int i = 0; i < 32; i++) {
            float4 ww = wrow[i], h = hv[i];
            acc += ww.x * h.x + ww.y * h.y + ww.z * h.z + ww.w * h.w;
        }
        z[j] = acc;
    }
    __syncthreads();

    if (j < OO) {
        const float4* __restrict__ wrow = (const float4*)(W2 + j * HH);
        const float4* __restrict__ zv   = (const float4*)z;
        float acc = b2[j];
#pragma unroll
        for (int i = 0; i < 32; i++) {
            float4 ww = wrow[i], zz = zv[i];
            acc += ww.x * zz.x + ww.y * zz.y + ww.z * zz.z + ww.w * zz.w;
        }
        out[r * OO + j] = acc;
    }
}

// ---------------------------------------------------------------------------
// Launch. Inputs: 0:x 1:W_ih 2:W_hh 3:b_ih 4:b_hh 5:W1 6:b1 7:W2 8:b2
// ws: xg packed (1 MB) | hs (128 KB) | Wp packed f16 frags (128 KB)
// ---------------------------------------------------------------------------
extern "C" void kernel_launch(void* const* d_in, const int* in_sizes, int n_in,
                              void* d_out, int out_size, void* d_ws, size_t ws_size,
                              hipStream_t stream) {
    const float* x    = (const float*)d_in[0];
    const float* W_ih = (const float*)d_in[1];
    const float* W_hh = (const float*)d_in[2];
    const float* b_ih = (const float*)d_in[3];
    const float* b_hh = (const float*)d_in[4];
    const float* W1   = (const float*)d_in[5];
    const float* b1   = (const float*)d_in[6];
    const float* W2   = (const float*)d_in[7];
    const float* b2   = (const float*)d_in[8];
    float* out = (float*)d_out;

    float*    xg = (float*)d_ws;                 // T*4H   = 262144 f32 (packed)
    float*    hs = xg + TT * GG;                 // 256*H  =  32768 f32
    _Float16* Wp = (_Float16*)(hs + BB * HH);    // 4H*H   =  65536 f16 (packed frags)

    xgpack_kernel<<<TT + 16, 512, 0, stream>>>(x, W_ih, b_ih, b_hh, W_hh, xg, Wp);
    scan_kernel<<<1, 256, 0, stream>>>(Wp, xg, hs);
    mlp_kernel<<<BB, 128, 0, stream>>>(hs, W1, b1, W2, b2, out);
}